// Round 1
// baseline (629.179 us; speedup 1.0000x reference)
//
#include <hip/hip_runtime.h>
#include <hip/hip_bf16.h>
#include <stdint.h>

#define B_ 2
#define S_ 2048
#define H_ 1024
#define I_ 2048
#define E_ 8
#define TOK (B_*S_)      // 4096 tokens
#define PAIRS (TOK*2)    // 8192 token-expert pairs

typedef __bf16 bf16_t;
typedef __bf16 bf16x4 __attribute__((ext_vector_type(4)));
typedef __bf16 bf16x8 __attribute__((ext_vector_type(8)));
typedef float  f32x4  __attribute__((ext_vector_type(4)));

// async global->LDS, 16B per lane. LDS dest = wave-uniform base + lane*16.
__device__ __forceinline__ void gl_lds16(const bf16_t* g, bf16_t* l) {
    __builtin_amdgcn_global_load_lds(
        (const __attribute__((address_space(1))) unsigned int*)g,
        (__attribute__((address_space(3))) unsigned int*)l, 16, 0, 0);
}

// ---------------- Router: logits = x @ Wg, softmax, top-2, renorm ----------------
__global__ void router_kernel(const float* __restrict__ x, const float* __restrict__ Wg,
                              int* __restrict__ top2e, float* __restrict__ top2w,
                              int* __restrict__ counts) {
    int wave = threadIdx.x >> 6;
    int lane = threadIdx.x & 63;
    int t = blockIdx.x * 4 + wave;
    if (t >= TOK) return;
    float acc[E_];
#pragma unroll
    for (int e = 0; e < E_; e++) acc[e] = 0.f;
    const float* xrow = x + (size_t)t * H_;
    for (int j = 0; j < H_ / 64; j++) {
        int h = j * 64 + lane;
        float xv = xrow[h];
        const float4* wg = (const float4*)(Wg + (size_t)h * E_);
        float4 w0 = wg[0], w1 = wg[1];
        acc[0] += xv * w0.x; acc[1] += xv * w0.y; acc[2] += xv * w0.z; acc[3] += xv * w0.w;
        acc[4] += xv * w1.x; acc[5] += xv * w1.y; acc[6] += xv * w1.z; acc[7] += xv * w1.w;
    }
#pragma unroll
    for (int e = 0; e < E_; e++) {
#pragma unroll
        for (int m = 32; m >= 1; m >>= 1) acc[e] += __shfl_xor(acc[e], m, 64);
    }
    if (lane == 0) {
        float mx = acc[0];
        for (int e = 1; e < E_; e++) mx = fmaxf(mx, acc[e]);
        float p[E_]; float z = 0.f;
        for (int e = 0; e < E_; e++) { p[e] = __expf(acc[e] - mx); z += p[e]; }
        for (int e = 0; e < E_; e++) p[e] /= z;
        int i1 = 0; float p1 = p[0];
        for (int e = 1; e < E_; e++) if (p[e] > p1) { p1 = p[e]; i1 = e; }
        int i2 = -1; float p2 = -1.f;
        for (int e = 0; e < E_; e++) if (e != i1 && p[e] > p2) { p2 = p[e]; i2 = e; }
        float s = p1 + p2 + 1e-8f;
        top2e[t * 2]     = i1; top2e[t * 2 + 1] = i2;
        top2w[t * 2]     = p1 / s; top2w[t * 2 + 1] = p2 / s;
        atomicAdd(&counts[i1], 1);
        atomicAdd(&counts[i2], 1);
    }
}

__global__ void scan_kernel(const int* __restrict__ counts, int* __restrict__ offsets,
                            int* __restrict__ cursor) {
    if (threadIdx.x == 0 && blockIdx.x == 0) {
        int run = 0;
        for (int e = 0; e < E_; e++) { offsets[e] = run; cursor[e] = run; run += counts[e]; }
    }
}

__global__ void fill_kernel(const int* __restrict__ top2e, const float* __restrict__ top2w,
                            int* __restrict__ cursor, int* __restrict__ pair_tok,
                            float* __restrict__ pair_w) {
    int t = blockIdx.x * blockDim.x + threadIdx.x;
    if (t >= TOK) return;
#pragma unroll
    for (int k = 0; k < 2; k++) {
        int e = top2e[t * 2 + k];
        int pos = atomicAdd(&cursor[e], 1);
        pair_tok[pos] = t;
        pair_w[pos]   = top2w[t * 2 + k];
    }
}

// ---------------- casts ----------------
__global__ void castx_kernel(const float* __restrict__ x, bf16_t* __restrict__ xb) {
    size_t i = ((size_t)blockIdx.x * blockDim.x + threadIdx.x) * 4;
    float4 v = *(const float4*)(x + i);
    bf16x4 o = { (bf16_t)v.x, (bf16_t)v.y, (bf16_t)v.z, (bf16_t)v.w };
    *(bf16x4*)(xb + i) = o;
}

// src: [E][R][C] fp32  ->  dst: [E][C][R] bf16
__global__ void transpose_cast_kernel(const float* __restrict__ src, bf16_t* __restrict__ dst,
                                      int R, int C) {
    __shared__ float tile[32][33];
    int e = blockIdx.z;
    const float* s = src + (size_t)e * R * C;
    bf16_t* d = dst + (size_t)e * R * C;
    int c0 = blockIdx.x * 32, r0 = blockIdx.y * 32;
#pragma unroll
    for (int j = 0; j < 4; j++) {
        int r = r0 + threadIdx.y + j * 8;
        tile[threadIdx.y + j * 8][threadIdx.x] = s[(size_t)r * C + c0 + threadIdx.x];
    }
    __syncthreads();
#pragma unroll
    for (int j = 0; j < 4; j++) {
        int c = c0 + threadIdx.y + j * 8;
        d[(size_t)c * R + r0 + threadIdx.x] = (bf16_t)tile[threadIdx.x][threadIdx.y + j * 8];
    }
}

// ---------------- GEMM1: fused = SiLU(x@W11) * (x@W12), per routed pair ----------------
// block tile: 128 m-rows x 64 i-cols, B-LDS rows 0..63 = W11t, 64..127 = W12t
__global__ __launch_bounds__(256) void gemm1_kernel(
    const bf16_t* __restrict__ xb,       // [TOK][H]
    const bf16_t* __restrict__ W11t,     // [E][I][H]
    const bf16_t* __restrict__ W12t,     // [E][I][H]
    const int* __restrict__ counts, const int* __restrict__ offsets,
    const int* __restrict__ pair_tok,
    bf16_t* __restrict__ fused)          // [PAIRS][I]
{
    int e = blockIdx.z;
    int cnt = counts[e];
    int m0 = blockIdx.y * 128;
    if (m0 >= cnt) return;
    int off = offsets[e];
    int n0 = blockIdx.x * 64;

    __shared__ __align__(16) bf16_t la[128 * 64];
    __shared__ __align__(16) bf16_t lb[128 * 64];

    int tid = threadIdx.x;
    int w = tid >> 6, lane = tid & 63;
    int lrow = lane >> 3, lcol = lane & 7;

    const bf16_t* aptr[4];
    const bf16_t* bptr[4];
#pragma unroll
    for (int it = 0; it < 4; it++) {
        int r = it * 32 + w * 8 + lrow;
        int grow = m0 + r;
        int tok = pair_tok[off + (grow < cnt ? grow : 0)];
        aptr[it] = xb + (size_t)tok * H_ + lcol * 8;
        const bf16_t* base = (r < 64)
            ? (W11t + ((size_t)e * I_ + n0 + r) * H_)
            : (W12t + ((size_t)e * I_ + n0 + (r - 64)) * H_);
        bptr[it] = base + lcol * 8;
    }

    f32x4 acc[2][8];
#pragma unroll
    for (int a = 0; a < 2; a++)
#pragma unroll
        for (int b = 0; b < 8; b++) acc[a][b] = (f32x4){0.f, 0.f, 0.f, 0.f};

    for (int k0 = 0; k0 < H_; k0 += 64) {
#pragma unroll
        for (int it = 0; it < 4; it++) {
            gl_lds16(aptr[it] + k0, &la[(it * 32 + w * 8) * 64]);
            gl_lds16(bptr[it] + k0, &lb[(it * 32 + w * 8) * 64]);
        }
        __syncthreads();
        int q8 = (lane >> 4) * 8;
        int c16 = lane & 15;
#pragma unroll
        for (int kk = 0; kk < 64; kk += 32) {
            bf16x8 af[2], bfr[8];
#pragma unroll
            for (int ms = 0; ms < 2; ms++)
                af[ms] = *(const bf16x8*)&la[(w * 32 + ms * 16 + c16) * 64 + kk + q8];
#pragma unroll
            for (int ns = 0; ns < 8; ns++)
                bfr[ns] = *(const bf16x8*)&lb[(ns * 16 + c16) * 64 + kk + q8];
#pragma unroll
            for (int ms = 0; ms < 2; ms++)
#pragma unroll
                for (int ns = 0; ns < 8; ns++)
                    acc[ms][ns] = __builtin_amdgcn_mfma_f32_16x16x32_bf16(
                        af[ms], bfr[ns], acc[ms][ns], 0, 0, 0);
        }
        __syncthreads();
    }

    int col = lane & 15;
#pragma unroll
    for (int ms = 0; ms < 2; ms++) {
#pragma unroll
        for (int ns = 0; ns < 4; ns++) {
            f32x4 g = acc[ms][ns], v = acc[ms][ns + 4];
#pragma unroll
            for (int r = 0; r < 4; r++) {
                int mrow = w * 32 + ms * 16 + (lane >> 4) * 4 + r;
                int grow = m0 + mrow;
                if (grow < cnt) {
                    float gg = g[r];
                    float f = gg * v[r] / (1.f + __expf(-gg));
                    int i = n0 + ns * 16 + col;
                    fused[(size_t)(off + grow) * I_ + i] = (bf16_t)f;
                }
            }
        }
    }
}

// ---------------- GEMM2: out[token] += w * (fused @ W2) ----------------
__global__ __launch_bounds__(256) void gemm2_kernel(
    const bf16_t* __restrict__ fused,    // [PAIRS][I]
    const bf16_t* __restrict__ W2t,      // [E][H][I]
    const int* __restrict__ counts, const int* __restrict__ offsets,
    const int* __restrict__ pair_tok, const float* __restrict__ pair_w,
    float* __restrict__ out)             // [TOK][H]
{
    int e = blockIdx.z;
    int cnt = counts[e];
    int m0 = blockIdx.y * 128;
    if (m0 >= cnt) return;
    int off = offsets[e];
    int n0 = blockIdx.x * 128;

    __shared__ __align__(16) bf16_t la[128 * 64];
    __shared__ __align__(16) bf16_t lb[128 * 64];

    int tid = threadIdx.x;
    int w = tid >> 6, lane = tid & 63;
    int lrow = lane >> 3, lcol = lane & 7;

    const bf16_t* aptr[4];
    const bf16_t* bptr[4];
#pragma unroll
    for (int it = 0; it < 4; it++) {
        int r = it * 32 + w * 8 + lrow;
        int grow = m0 + r;
        if (grow >= cnt) grow = cnt - 1;
        aptr[it] = fused + (size_t)(off + grow) * I_ + lcol * 8;
        bptr[it] = W2t + ((size_t)e * H_ + n0 + r) * I_ + lcol * 8;
    }

    f32x4 acc[2][8];
#pragma unroll
    for (int a = 0; a < 2; a++)
#pragma unroll
        for (int b = 0; b < 8; b++) acc[a][b] = (f32x4){0.f, 0.f, 0.f, 0.f};

    for (int k0 = 0; k0 < I_; k0 += 64) {
#pragma unroll
        for (int it = 0; it < 4; it++) {
            gl_lds16(aptr[it] + k0, &la[(it * 32 + w * 8) * 64]);
            gl_lds16(bptr[it] + k0, &lb[(it * 32 + w * 8) * 64]);
        }
        __syncthreads();
        int q8 = (lane >> 4) * 8;
        int c16 = lane & 15;
#pragma unroll
        for (int kk = 0; kk < 64; kk += 32) {
            bf16x8 af[2], bfr[8];
#pragma unroll
            for (int ms = 0; ms < 2; ms++)
                af[ms] = *(const bf16x8*)&la[(w * 32 + ms * 16 + c16) * 64 + kk + q8];
#pragma unroll
            for (int ns = 0; ns < 8; ns++)
                bfr[ns] = *(const bf16x8*)&lb[(ns * 16 + c16) * 64 + kk + q8];
#pragma unroll
            for (int ms = 0; ms < 2; ms++)
#pragma unroll
                for (int ns = 0; ns < 8; ns++)
                    acc[ms][ns] = __builtin_amdgcn_mfma_f32_16x16x32_bf16(
                        af[ms], bfr[ns], acc[ms][ns], 0, 0, 0);
        }
        __syncthreads();
    }

    int col = lane & 15;
#pragma unroll
    for (int ms = 0; ms < 2; ms++) {
#pragma unroll
        for (int r = 0; r < 4; r++) {
            int mrow = w * 32 + ms * 16 + (lane >> 4) * 4 + r;
            int grow = m0 + mrow;
            if (grow < cnt) {
                int slot = off + grow;
                int tok = pair_tok[slot];
                float wt = pair_w[slot];
#pragma unroll
                for (int ns = 0; ns < 8; ns++) {
                    atomicAdd(&out[(size_t)tok * H_ + n0 + ns * 16 + col], wt * acc[ms][ns][r]);
                }
            }
        }
    }
}

// ---------------- host ----------------
extern "C" void kernel_launch(void* const* d_in, const int* in_sizes, int n_in,
                              void* d_out, int out_size, void* d_ws, size_t ws_size,
                              hipStream_t stream) {
    const float* x   = (const float*)d_in[0];
    const float* Wg  = (const float*)d_in[1];
    const float* W11 = (const float*)d_in[2];
    const float* W12 = (const float*)d_in[3];
    const float* W2  = (const float*)d_in[4];
    float* out = (float*)d_out;

    char* ws = (char*)d_ws;
    size_t o = 0;
    auto alloc = [&](size_t bytes) { size_t r = o; o = (o + bytes + 255) & ~(size_t)255; return r; };
    int*    counts   = (int*)(ws + alloc(E_ * 4));
    int*    offsets  = (int*)(ws + alloc(E_ * 4));
    int*    cursor   = (int*)(ws + alloc(E_ * 4));
    int*    top2e    = (int*)(ws + alloc(TOK * 2 * 4));
    float*  top2w    = (float*)(ws + alloc(TOK * 2 * 4));
    int*    pair_tok = (int*)(ws + alloc(PAIRS * 4));
    float*  pair_w   = (float*)(ws + alloc(PAIRS * 4));
    bf16_t* xb       = (bf16_t*)(ws + alloc((size_t)TOK * H_ * 2));
    bf16_t* W11t     = (bf16_t*)(ws + alloc((size_t)E_ * I_ * H_ * 2));
    bf16_t* W12t     = (bf16_t*)(ws + alloc((size_t)E_ * I_ * H_ * 2));
    bf16_t* W2t      = (bf16_t*)(ws + alloc((size_t)E_ * I_ * H_ * 2));
    bf16_t* fusedbuf = (bf16_t*)(ws + alloc((size_t)PAIRS * I_ * 2));

    hipMemsetAsync(counts, 0, E_ * 4, stream);
    hipMemsetAsync(d_out, 0, (size_t)out_size * 4, stream);

    router_kernel<<<TOK / 4, 256, 0, stream>>>(x, Wg, top2e, top2w, counts);
    scan_kernel<<<1, 64, 0, stream>>>(counts, offsets, cursor);
    fill_kernel<<<TOK / 256, 256, 0, stream>>>(top2e, top2w, cursor, pair_tok, pair_w);

    castx_kernel<<<(TOK * H_ / 4) / 256, 256, 0, stream>>>(x, xb);
    // W11: [E][H][I] -> [E][I][H]
    transpose_cast_kernel<<<dim3(I_ / 32, H_ / 32, E_), dim3(32, 8), 0, stream>>>(W11, W11t, H_, I_);
    transpose_cast_kernel<<<dim3(I_ / 32, H_ / 32, E_), dim3(32, 8), 0, stream>>>(W12, W12t, H_, I_);
    // W2: [E][I][H] -> [E][H][I]
    transpose_cast_kernel<<<dim3(H_ / 32, I_ / 32, E_), dim3(32, 8), 0, stream>>>(W2, W2t, I_, H_);

    gemm1_kernel<<<dim3(I_ / 64, 32, E_), 256, 0, stream>>>(
        xb, W11t, W12t, counts, offsets, pair_tok, fusedbuf);
    gemm2_kernel<<<dim3(H_ / 128, 32, E_), 256, 0, stream>>>(
        fusedbuf, W2t, counts, offsets, pair_tok, pair_w, out);
}

// Round 2
// 597.724 us; speedup vs baseline: 1.0526x; 1.0526x over previous
//
#include <hip/hip_runtime.h>
#include <hip/hip_bf16.h>
#include <stdint.h>

#define B_ 2
#define S_ 2048
#define H_ 1024
#define I_ 2048
#define E_ 8
#define TOK (B_*S_)      // 4096 tokens
#define PAIRS (TOK*2)    // 8192 token-expert pairs
#define MAXBLK 80        // max sum_e ceil(cnt_e/128) = 64+7=71

typedef __bf16 bf16_t;
typedef __bf16 bf16x4 __attribute__((ext_vector_type(4)));
typedef __bf16 bf16x8 __attribute__((ext_vector_type(8)));
typedef float  f32x4  __attribute__((ext_vector_type(4)));

// async global->LDS, 16B per lane. LDS dest = wave-uniform base + lane*16.
__device__ __forceinline__ void gl_lds16(const bf16_t* g, bf16_t* l) {
    __builtin_amdgcn_global_load_lds(
        (const __attribute__((address_space(1))) unsigned int*)g,
        (__attribute__((address_space(3))) unsigned int*)l, 16, 0, 0);
}

// ---------------- Router ----------------
__global__ void router_kernel(const float* __restrict__ x, const float* __restrict__ Wg,
                              int* __restrict__ top2e, float* __restrict__ top2w,
                              int* __restrict__ counts) {
    int wave = threadIdx.x >> 6;
    int lane = threadIdx.x & 63;
    int t = blockIdx.x * 4 + wave;
    if (t >= TOK) return;
    float acc[E_];
#pragma unroll
    for (int e = 0; e < E_; e++) acc[e] = 0.f;
    const float* xrow = x + (size_t)t * H_;
    for (int j = 0; j < H_ / 64; j++) {
        int h = j * 64 + lane;
        float xv = xrow[h];
        const float4* wg = (const float4*)(Wg + (size_t)h * E_);
        float4 w0 = wg[0], w1 = wg[1];
        acc[0] += xv * w0.x; acc[1] += xv * w0.y; acc[2] += xv * w0.z; acc[3] += xv * w0.w;
        acc[4] += xv * w1.x; acc[5] += xv * w1.y; acc[6] += xv * w1.z; acc[7] += xv * w1.w;
    }
#pragma unroll
    for (int e = 0; e < E_; e++) {
#pragma unroll
        for (int m = 32; m >= 1; m >>= 1) acc[e] += __shfl_xor(acc[e], m, 64);
    }
    if (lane == 0) {
        float mx = acc[0];
        for (int e = 1; e < E_; e++) mx = fmaxf(mx, acc[e]);
        float p[E_]; float z = 0.f;
        for (int e = 0; e < E_; e++) { p[e] = __expf(acc[e] - mx); z += p[e]; }
        for (int e = 0; e < E_; e++) p[e] /= z;
        int i1 = 0; float p1 = p[0];
        for (int e = 1; e < E_; e++) if (p[e] > p1) { p1 = p[e]; i1 = e; }
        int i2 = -1; float p2 = -1.f;
        for (int e = 0; e < E_; e++) if (e != i1 && p[e] > p2) { p2 = p[e]; i2 = e; }
        float s = p1 + p2 + 1e-8f;
        top2e[t * 2]     = i1; top2e[t * 2 + 1] = i2;
        top2w[t * 2]     = p1 / s; top2w[t * 2 + 1] = p2 / s;
        atomicAdd(&counts[i1], 1);
        atomicAdd(&counts[i2], 1);
    }
}

// scan + build block schedule (expert, m0) for 128-row m-tiles
__global__ void scan_kernel(const int* __restrict__ counts, int* __restrict__ offsets,
                            int* __restrict__ cursor, int* __restrict__ blk_e,
                            int* __restrict__ blk_m0, int* __restrict__ nblk) {
    if (threadIdx.x == 0 && blockIdx.x == 0) {
        int run = 0, b = 0;
        for (int e = 0; e < E_; e++) {
            offsets[e] = run; cursor[e] = run;
            int c = counts[e];
            for (int m0 = 0; m0 < c; m0 += 128) { blk_e[b] = e; blk_m0[b] = m0; b++; }
            run += c;
        }
        nblk[0] = b;
    }
}

__global__ void fill_kernel(const int* __restrict__ top2e, const float* __restrict__ top2w,
                            int* __restrict__ cursor, int* __restrict__ pair_tok,
                            float* __restrict__ pair_w) {
    int t = blockIdx.x * blockDim.x + threadIdx.x;
    if (t >= TOK) return;
#pragma unroll
    for (int k = 0; k < 2; k++) {
        int e = top2e[t * 2 + k];
        int pos = atomicAdd(&cursor[e], 1);
        pair_tok[pos] = t;
        pair_w[pos]   = top2w[t * 2 + k];
    }
}

// ---------------- casts ----------------
__global__ void castx_kernel(const float* __restrict__ x, bf16_t* __restrict__ xb) {
    size_t i = ((size_t)blockIdx.x * blockDim.x + threadIdx.x) * 4;
    float4 v = *(const float4*)(x + i);
    bf16x4 o = { (bf16_t)v.x, (bf16_t)v.y, (bf16_t)v.z, (bf16_t)v.w };
    *(bf16x4*)(xb + i) = o;
}

// src: [E][R][C] fp32 -> dst: [E][C][R] bf16, 64x64 tiles, vectorized both sides
__global__ __launch_bounds__(256) void transpose_cast_kernel(
    const float* __restrict__ src, bf16_t* __restrict__ dst, int R, int C) {
    __shared__ float tile[64][65];
    int e = blockIdx.z;
    const float* s = src + (size_t)e * R * C;
    bf16_t* d = dst + (size_t)e * R * C;
    int c0 = blockIdx.x * 64, r0 = blockIdx.y * 64;
    int t = threadIdx.x;
    int lr = t >> 4, lc = (t & 15) * 4;
#pragma unroll
    for (int j = 0; j < 4; j++) {
        int r = r0 + lr + j * 16;
        float4 v = *(const float4*)(s + (size_t)r * C + c0 + lc);
        tile[lr + j * 16][lc + 0] = v.x;
        tile[lr + j * 16][lc + 1] = v.y;
        tile[lr + j * 16][lc + 2] = v.z;
        tile[lr + j * 16][lc + 3] = v.w;
    }
    __syncthreads();
    int oc = t >> 2, os = (t & 3) * 8;
#pragma unroll
    for (int j = 0; j < 2; j++) {
        int base = os + j * 32;
        bf16x8 v;
#pragma unroll
        for (int k = 0; k < 8; k++) v[k] = (bf16_t)tile[base + k][oc];
        *(bf16x8*)(d + (size_t)(c0 + oc) * R + r0 + base) = v;
    }
}

// ---------------- GEMM1: fused = SiLU(x@W11) * (x@W12) ----------------
// 128 m-rows x 64 i-cols; B-LDS rows 0..63 = W11t, 64..127 = W12t.
// LDS layout XOR-swizzled: physical slot s^(row&7) holds logical 16B seg s.
__global__ __launch_bounds__(256) void gemm1_kernel(
    const bf16_t* __restrict__ xb,       // [TOK][H]
    const bf16_t* __restrict__ W11t,     // [E][I][H]
    const bf16_t* __restrict__ W12t,     // [E][I][H]
    const int* __restrict__ counts, const int* __restrict__ offsets,
    const int* __restrict__ blk_e, const int* __restrict__ blk_m0,
    const int* __restrict__ nblk,
    const int* __restrict__ pair_tok,
    bf16_t* __restrict__ fused)          // [PAIRS][I]
{
    int by = blockIdx.y;
    if (by >= nblk[0]) return;
    int e = blk_e[by];
    int m0 = blk_m0[by];
    int cnt = counts[e];
    int off = offsets[e];
    int n0 = blockIdx.x * 64;

    __shared__ __align__(16) bf16_t la[128 * 64];
    __shared__ __align__(16) bf16_t lb[128 * 64];

    int tid = threadIdx.x;
    int w = tid >> 6, lane = tid & 63;
    int lrow = lane >> 3, lcol = lane & 7;
    int scol = lcol ^ lrow;              // swizzled source segment

    const bf16_t* aptr[4];
    const bf16_t* bptr[4];
#pragma unroll
    for (int it = 0; it < 4; it++) {
        int r = it * 32 + w * 8 + lrow;
        int grow = m0 + r;
        int tok = pair_tok[off + (grow < cnt ? grow : 0)];
        aptr[it] = xb + (size_t)tok * H_ + scol * 8;
        const bf16_t* base = (r < 64)
            ? (W11t + ((size_t)e * I_ + n0 + r) * H_)
            : (W12t + ((size_t)e * I_ + n0 + (r - 64)) * H_);
        bptr[it] = base + scol * 8;
    }

    f32x4 acc[2][8];
#pragma unroll
    for (int a = 0; a < 2; a++)
#pragma unroll
        for (int b = 0; b < 8; b++) acc[a][b] = (f32x4){0.f, 0.f, 0.f, 0.f};

    for (int k0 = 0; k0 < H_; k0 += 64) {
#pragma unroll
        for (int it = 0; it < 4; it++) {
            gl_lds16(aptr[it] + k0, &la[(it * 32 + w * 8) * 64]);
            gl_lds16(bptr[it] + k0, &lb[(it * 32 + w * 8) * 64]);
        }
        __syncthreads();
        int q8 = (lane >> 4) * 8;
        int c16 = lane & 15;
        int rx = c16 & 7;
#pragma unroll
        for (int kk = 0; kk < 64; kk += 32) {
            int slot = ((kk + q8) >> 3) ^ rx;
            bf16x8 af[2], bfr[8];
#pragma unroll
            for (int ms = 0; ms < 2; ms++)
                af[ms] = *(const bf16x8*)&la[(w * 32 + ms * 16 + c16) * 64 + slot * 8];
#pragma unroll
            for (int ns = 0; ns < 8; ns++)
                bfr[ns] = *(const bf16x8*)&lb[(ns * 16 + c16) * 64 + slot * 8];
#pragma unroll
            for (int ms = 0; ms < 2; ms++)
#pragma unroll
                for (int ns = 0; ns < 8; ns++)
                    acc[ms][ns] = __builtin_amdgcn_mfma_f32_16x16x32_bf16(
                        af[ms], bfr[ns], acc[ms][ns], 0, 0, 0);
        }
        __syncthreads();
    }

    int col = lane & 15;
#pragma unroll
    for (int ms = 0; ms < 2; ms++) {
#pragma unroll
        for (int ns = 0; ns < 4; ns++) {
            f32x4 g = acc[ms][ns], v = acc[ms][ns + 4];
#pragma unroll
            for (int r = 0; r < 4; r++) {
                int mrow = w * 32 + ms * 16 + (lane >> 4) * 4 + r;
                int grow = m0 + mrow;
                if (grow < cnt) {
                    float gg = g[r];
                    float f = gg * v[r] / (1.f + __expf(-gg));
                    int i = n0 + ns * 16 + col;
                    fused[(size_t)(off + grow) * I_ + i] = (bf16_t)f;
                }
            }
        }
    }
}

// ---------------- GEMM2: out[token] += w * (fused @ W2) ----------------
__global__ __launch_bounds__(256) void gemm2_kernel(
    const bf16_t* __restrict__ fused,    // [PAIRS][I]
    const bf16_t* __restrict__ W2t,      // [E][H][I]
    const int* __restrict__ counts, const int* __restrict__ offsets,
    const int* __restrict__ blk_e, const int* __restrict__ blk_m0,
    const int* __restrict__ nblk,
    const int* __restrict__ pair_tok, const float* __restrict__ pair_w,
    float* __restrict__ out)             // [TOK][H]
{
    int by = blockIdx.y;
    if (by >= nblk[0]) return;
    int e = blk_e[by];
    int m0 = blk_m0[by];
    int cnt = counts[e];
    int off = offsets[e];
    int n0 = blockIdx.x * 128;

    __shared__ __align__(16) bf16_t la[128 * 64];
    __shared__ __align__(16) bf16_t lb[128 * 64];

    int tid = threadIdx.x;
    int w = tid >> 6, lane = tid & 63;
    int lrow = lane >> 3, lcol = lane & 7;
    int scol = lcol ^ lrow;

    const bf16_t* aptr[4];
    const bf16_t* bptr[4];
#pragma unroll
    for (int it = 0; it < 4; it++) {
        int r = it * 32 + w * 8 + lrow;
        int grow = m0 + r;
        if (grow >= cnt) grow = cnt - 1;
        aptr[it] = fused + (size_t)(off + grow) * I_ + scol * 8;
        bptr[it] = W2t + ((size_t)e * H_ + n0 + r) * I_ + scol * 8;
    }

    f32x4 acc[2][8];
#pragma unroll
    for (int a = 0; a < 2; a++)
#pragma unroll
        for (int b = 0; b < 8; b++) acc[a][b] = (f32x4){0.f, 0.f, 0.f, 0.f};

    for (int k0 = 0; k0 < I_; k0 += 64) {
#pragma unroll
        for (int it = 0; it < 4; it++) {
            gl_lds16(aptr[it] + k0, &la[(it * 32 + w * 8) * 64]);
            gl_lds16(bptr[it] + k0, &lb[(it * 32 + w * 8) * 64]);
        }
        __syncthreads();
        int q8 = (lane >> 4) * 8;
        int c16 = lane & 15;
        int rx = c16 & 7;
#pragma unroll
        for (int kk = 0; kk < 64; kk += 32) {
            int slot = ((kk + q8) >> 3) ^ rx;
            bf16x8 af[2], bfr[8];
#pragma unroll
            for (int ms = 0; ms < 2; ms++)
                af[ms] = *(const bf16x8*)&la[(w * 32 + ms * 16 + c16) * 64 + slot * 8];
#pragma unroll
            for (int ns = 0; ns < 8; ns++)
                bfr[ns] = *(const bf16x8*)&lb[(ns * 16 + c16) * 64 + slot * 8];
#pragma unroll
            for (int ms = 0; ms < 2; ms++)
#pragma unroll
                for (int ns = 0; ns < 8; ns++)
                    acc[ms][ns] = __builtin_amdgcn_mfma_f32_16x16x32_bf16(
                        af[ms], bfr[ns], acc[ms][ns], 0, 0, 0);
        }
        __syncthreads();
    }

    int col = lane & 15;
#pragma unroll
    for (int ms = 0; ms < 2; ms++) {
#pragma unroll
        for (int r = 0; r < 4; r++) {
            int mrow = w * 32 + ms * 16 + (lane >> 4) * 4 + r;
            int grow = m0 + mrow;
            if (grow < cnt) {
                int slot = off + grow;
                int tok = pair_tok[slot];
                float wt = pair_w[slot];
#pragma unroll
                for (int ns = 0; ns < 8; ns++) {
                    atomicAdd(&out[(size_t)tok * H_ + n0 + ns * 16 + col], wt * acc[ms][ns][r]);
                }
            }
        }
    }
}

// ---------------- host ----------------
extern "C" void kernel_launch(void* const* d_in, const int* in_sizes, int n_in,
                              void* d_out, int out_size, void* d_ws, size_t ws_size,
                              hipStream_t stream) {
    const float* x   = (const float*)d_in[0];
    const float* Wg  = (const float*)d_in[1];
    const float* W11 = (const float*)d_in[2];
    const float* W12 = (const float*)d_in[3];
    const float* W2  = (const float*)d_in[4];
    float* out = (float*)d_out;

    char* ws = (char*)d_ws;
    size_t o = 0;
    auto alloc = [&](size_t bytes) { size_t r = o; o = (o + bytes + 255) & ~(size_t)255; return r; };
    int*    counts   = (int*)(ws + alloc(E_ * 4));
    int*    offsets  = (int*)(ws + alloc(E_ * 4));
    int*    cursor   = (int*)(ws + alloc(E_ * 4));
    int*    blk_e    = (int*)(ws + alloc(MAXBLK * 4));
    int*    blk_m0   = (int*)(ws + alloc(MAXBLK * 4));
    int*    nblk     = (int*)(ws + alloc(4));
    int*    top2e    = (int*)(ws + alloc(TOK * 2 * 4));
    float*  top2w    = (float*)(ws + alloc(TOK * 2 * 4));
    int*    pair_tok = (int*)(ws + alloc(PAIRS * 4));
    float*  pair_w   = (float*)(ws + alloc(PAIRS * 4));
    bf16_t* xb       = (bf16_t*)(ws + alloc((size_t)TOK * H_ * 2));
    bf16_t* W11t     = (bf16_t*)(ws + alloc((size_t)E_ * I_ * H_ * 2));
    bf16_t* W12t     = (bf16_t*)(ws + alloc((size_t)E_ * I_ * H_ * 2));
    bf16_t* W2t      = (bf16_t*)(ws + alloc((size_t)E_ * I_ * H_ * 2));
    bf16_t* fusedbuf = (bf16_t*)(ws + alloc((size_t)PAIRS * I_ * 2));

    hipMemsetAsync(counts, 0, E_ * 4, stream);
    hipMemsetAsync(d_out, 0, (size_t)out_size * 4, stream);

    router_kernel<<<TOK / 4, 256, 0, stream>>>(x, Wg, top2e, top2w, counts);
    scan_kernel<<<1, 64, 0, stream>>>(counts, offsets, cursor, blk_e, blk_m0, nblk);
    fill_kernel<<<TOK / 256, 256, 0, stream>>>(top2e, top2w, cursor, pair_tok, pair_w);

    castx_kernel<<<(TOK * H_ / 4) / 256, 256, 0, stream>>>(x, xb);
    // W11/W12: [E][H][I] -> [E][I][H]
    transpose_cast_kernel<<<dim3(I_ / 64, H_ / 64, E_), 256, 0, stream>>>(W11, W11t, H_, I_);
    transpose_cast_kernel<<<dim3(I_ / 64, H_ / 64, E_), 256, 0, stream>>>(W12, W12t, H_, I_);
    // W2: [E][I][H] -> [E][H][I]
    transpose_cast_kernel<<<dim3(H_ / 64, I_ / 64, E_), 256, 0, stream>>>(W2, W2t, I_, H_);

    gemm1_kernel<<<dim3(I_ / 64, MAXBLK), 256, 0, stream>>>(
        xb, W11t, W12t, counts, offsets, blk_e, blk_m0, nblk, pair_tok, fusedbuf);
    gemm2_kernel<<<dim3(H_ / 128, MAXBLK), 256, 0, stream>>>(
        fusedbuf, W2t, counts, offsets, blk_e, blk_m0, nblk, pair_tok, pair_w, out);
}

// Round 3
// 541.185 us; speedup vs baseline: 1.1626x; 1.1045x over previous
//
#include <hip/hip_runtime.h>
#include <hip/hip_bf16.h>
#include <stdint.h>

#define B_ 2
#define S_ 2048
#define H_ 1024
#define I_ 2048
#define E_ 8
#define TOK (B_*S_)      // 4096 tokens
#define PAIRS (TOK*2)    // 8192 token-expert pairs
#define MAXBLK 80        // max sum_e ceil(cnt_e/128) = 64+7=71

typedef __bf16 bf16_t;
typedef __bf16 bf16x4 __attribute__((ext_vector_type(4)));
typedef __bf16 bf16x8 __attribute__((ext_vector_type(8)));
typedef float  f32x4  __attribute__((ext_vector_type(4)));
typedef float  f32x16 __attribute__((ext_vector_type(16)));

// async global->LDS, 16B per lane. LDS dest = wave-uniform base + lane*16.
__device__ __forceinline__ void gl_lds16(const bf16_t* g, bf16_t* l) {
    __builtin_amdgcn_global_load_lds(
        (const __attribute__((address_space(1))) unsigned int*)g,
        (__attribute__((address_space(3))) unsigned int*)l, 16, 0, 0);
}

// ---------------- Router ----------------
__global__ void router_kernel(const float* __restrict__ x, const float* __restrict__ Wg,
                              int* __restrict__ top2e, float* __restrict__ top2w,
                              int* __restrict__ counts) {
    int wave = threadIdx.x >> 6;
    int lane = threadIdx.x & 63;
    int t = blockIdx.x * 4 + wave;
    if (t >= TOK) return;
    float acc[E_];
#pragma unroll
    for (int e = 0; e < E_; e++) acc[e] = 0.f;
    const float* xrow = x + (size_t)t * H_;
    for (int j = 0; j < H_ / 64; j++) {
        int h = j * 64 + lane;
        float xv = xrow[h];
        const float4* wg = (const float4*)(Wg + (size_t)h * E_);
        float4 w0 = wg[0], w1 = wg[1];
        acc[0] += xv * w0.x; acc[1] += xv * w0.y; acc[2] += xv * w0.z; acc[3] += xv * w0.w;
        acc[4] += xv * w1.x; acc[5] += xv * w1.y; acc[6] += xv * w1.z; acc[7] += xv * w1.w;
    }
#pragma unroll
    for (int e = 0; e < E_; e++) {
#pragma unroll
        for (int m = 32; m >= 1; m >>= 1) acc[e] += __shfl_xor(acc[e], m, 64);
    }
    if (lane == 0) {
        float mx = acc[0];
        for (int e = 1; e < E_; e++) mx = fmaxf(mx, acc[e]);
        float p[E_]; float z = 0.f;
        for (int e = 0; e < E_; e++) { p[e] = __expf(acc[e] - mx); z += p[e]; }
        for (int e = 0; e < E_; e++) p[e] /= z;
        int i1 = 0; float p1 = p[0];
        for (int e = 1; e < E_; e++) if (p[e] > p1) { p1 = p[e]; i1 = e; }
        int i2 = -1; float p2 = -1.f;
        for (int e = 0; e < E_; e++) if (e != i1 && p[e] > p2) { p2 = p[e]; i2 = e; }
        float s = p1 + p2 + 1e-8f;
        top2e[t * 2]     = i1; top2e[t * 2 + 1] = i2;
        top2w[t * 2]     = p1 / s; top2w[t * 2 + 1] = p2 / s;
        atomicAdd(&counts[i1], 1);
        atomicAdd(&counts[i2], 1);
    }
}

// scan + build block schedule (expert, m0) for 128-row m-tiles
__global__ void scan_kernel(const int* __restrict__ counts, int* __restrict__ offsets,
                            int* __restrict__ cursor, int* __restrict__ blk_e,
                            int* __restrict__ blk_m0, int* __restrict__ nblk) {
    if (threadIdx.x == 0 && blockIdx.x == 0) {
        int run = 0, b = 0;
        for (int e = 0; e < E_; e++) {
            offsets[e] = run; cursor[e] = run;
            int c = counts[e];
            for (int m0 = 0; m0 < c; m0 += 128) { blk_e[b] = e; blk_m0[b] = m0; b++; }
            run += c;
        }
        nblk[0] = b;
    }
}

__global__ void fill_kernel(const int* __restrict__ top2e, const float* __restrict__ top2w,
                            int* __restrict__ cursor, int* __restrict__ pair_tok,
                            float* __restrict__ pair_w) {
    int t = blockIdx.x * blockDim.x + threadIdx.x;
    if (t >= TOK) return;
#pragma unroll
    for (int k = 0; k < 2; k++) {
        int e = top2e[t * 2 + k];
        int pos = atomicAdd(&cursor[e], 1);
        pair_tok[pos] = t;
        pair_w[pos]   = top2w[t * 2 + k];
    }
}

// ---------------- casts ----------------
__global__ void castx_kernel(const float* __restrict__ x, bf16_t* __restrict__ xb) {
    size_t i = ((size_t)blockIdx.x * blockDim.x + threadIdx.x) * 4;
    float4 v = *(const float4*)(x + i);
    bf16x4 o = { (bf16_t)v.x, (bf16_t)v.y, (bf16_t)v.z, (bf16_t)v.w };
    *(bf16x4*)(xb + i) = o;
}

// src: [E][R][C] fp32 -> dst: [E][C][R] bf16, 64x64 tiles, vectorized both sides
__global__ __launch_bounds__(256) void transpose_cast_kernel(
    const float* __restrict__ src, bf16_t* __restrict__ dst, int R, int C) {
    __shared__ float tile[64][65];
    int e = blockIdx.z;
    const float* s = src + (size_t)e * R * C;
    bf16_t* d = dst + (size_t)e * R * C;
    int c0 = blockIdx.x * 64, r0 = blockIdx.y * 64;
    int t = threadIdx.x;
    int lr = t >> 4, lc = (t & 15) * 4;
#pragma unroll
    for (int j = 0; j < 4; j++) {
        int r = r0 + lr + j * 16;
        float4 v = *(const float4*)(s + (size_t)r * C + c0 + lc);
        tile[lr + j * 16][lc + 0] = v.x;
        tile[lr + j * 16][lc + 1] = v.y;
        tile[lr + j * 16][lc + 2] = v.z;
        tile[lr + j * 16][lc + 3] = v.w;
    }
    __syncthreads();
    int oc = t >> 2, os = (t & 3) * 8;
#pragma unroll
    for (int j = 0; j < 2; j++) {
        int base = os + j * 32;
        bf16x8 v;
#pragma unroll
        for (int k = 0; k < 8; k++) v[k] = (bf16_t)tile[base + k][oc];
        *(bf16x8*)(d + (size_t)(c0 + oc) * R + r0 + base) = v;
    }
}

// ---------------- GEMM1: fused = SiLU(x@W11) * (x@W12) ----------------
// block: 128 m-rows x 128 i-cols (gate+value => N_eff=256), 32x32x16 MFMA.
// 4 waves in 2x2 grid; wave tile 64m x (64 gate + 64 value).
// LDS XOR-swizzle: physical 16B slot s^(row&7) holds logical seg s.
__global__ __launch_bounds__(256, 2) void gemm1_kernel(
    const bf16_t* __restrict__ xb,       // [TOK][H]
    const bf16_t* __restrict__ W11t,     // [E][I][H]
    const bf16_t* __restrict__ W12t,     // [E][I][H]
    const int* __restrict__ counts, const int* __restrict__ offsets,
    const int* __restrict__ blk_e, const int* __restrict__ blk_m0,
    const int* __restrict__ nblk,
    const int* __restrict__ pair_tok,
    bf16_t* __restrict__ fused)          // [PAIRS][I]
{
    int by = blockIdx.y;
    if (by >= nblk[0]) return;
    int e = blk_e[by];
    int m0 = blk_m0[by];
    int cnt = counts[e];
    int off = offsets[e];
    int n0 = blockIdx.x * 128;           // i-col base

    __shared__ __align__(16) bf16_t la[128 * 64];   // 16 KB
    __shared__ __align__(16) bf16_t lb[256 * 64];   // 32 KB: rows 0..127 gate, 128..255 value

    int tid = threadIdx.x;
    int w = tid >> 6, lane = tid & 63;
    int wm = w >> 1, wn = w & 1;
    int lrow = lane >> 3, lcol = lane & 7;
    int scol = lcol ^ lrow;              // swizzled source segment

    const bf16_t* aptr[2];
    const bf16_t* bptr[8];
#pragma unroll
    for (int it = 0; it < 2; it++) {     // A: 128 rows = 2 its of (4 waves x 8 rows)... need 4
        ;
    }
    // A: 128 rows staged in 4 its; B: 256 rows in 8 its
    const bf16_t* aptr4[4];
#pragma unroll
    for (int it = 0; it < 4; it++) {
        int r = it * 32 + w * 8 + lrow;
        int grow = m0 + r;
        int tok = pair_tok[off + (grow < cnt ? grow : 0)];
        aptr4[it] = xb + (size_t)tok * H_ + scol * 8;
    }
#pragma unroll
    for (int it = 0; it < 8; it++) {
        int r = it * 32 + w * 8 + lrow;  // 0..255
        const bf16_t* base = (r < 128)
            ? (W11t + ((size_t)e * I_ + n0 + r) * H_)
            : (W12t + ((size_t)e * I_ + n0 + (r - 128)) * H_);
        bptr[it] = base + scol * 8;
    }

    f32x16 acc[2][4];                    // [ms][ns]: ns 0,1 gate; 2,3 value
#pragma unroll
    for (int a = 0; a < 2; a++)
#pragma unroll
        for (int b = 0; b < 4; b++) acc[a][b] = (f32x16)(0.f);

    int r32 = lane & 31;
    int khalf = lane >> 5;               // 0/1 -> k-seg offset
    int rx = r32 & 7;

    for (int k0 = 0; k0 < H_; k0 += 64) {
#pragma unroll
        for (int it = 0; it < 4; it++)
            gl_lds16(aptr4[it] + k0, &la[(it * 32 + w * 8) * 64]);
#pragma unroll
        for (int it = 0; it < 8; it++)
            gl_lds16(bptr[it] + k0, &lb[(it * 32 + w * 8) * 64]);
        __syncthreads();
#pragma unroll
        for (int t16 = 0; t16 < 4; t16++) {
            int seg = t16 * 2 + khalf;
            bf16x8 af[2], bfr[4];
#pragma unroll
            for (int ms = 0; ms < 2; ms++) {
                int row = wm * 64 + ms * 32 + r32;
                af[ms] = *(const bf16x8*)&la[row * 64 + (seg ^ rx) * 8];
            }
#pragma unroll
            for (int ns = 0; ns < 2; ns++) {
                int browg = wn * 64 + ns * 32 + r32;
                bfr[ns]     = *(const bf16x8*)&lb[browg * 64 + (seg ^ rx) * 8];
                bfr[ns + 2] = *(const bf16x8*)&lb[(browg + 128) * 64 + (seg ^ rx) * 8];
            }
#pragma unroll
            for (int ms = 0; ms < 2; ms++)
#pragma unroll
                for (int ns = 0; ns < 4; ns++)
                    acc[ms][ns] = __builtin_amdgcn_mfma_f32_32x32x16_bf16(
                        af[ms], bfr[ns], acc[ms][ns], 0, 0, 0);
        }
        __syncthreads();
    }

    // C/D 32x32 layout: col=lane&31, row=(reg&3)+8*(reg>>2)+4*(lane>>5)
#pragma unroll
    for (int ms = 0; ms < 2; ms++) {
#pragma unroll
        for (int ns = 0; ns < 2; ns++) {
            int i = n0 + wn * 64 + ns * 32 + r32;
#pragma unroll
            for (int reg = 0; reg < 16; reg++) {
                int rrow = (reg & 3) + 8 * (reg >> 2) + 4 * khalf;
                int grow = m0 + wm * 64 + ms * 32 + rrow;
                if (grow < cnt) {
                    float g = acc[ms][ns][reg];
                    float v = acc[ms][ns + 2][reg];
                    float f = g * v / (1.f + __expf(-g));
                    fused[(size_t)(off + grow) * I_ + i] = (bf16_t)f;
                }
            }
        }
    }
}

// ---------------- GEMM2: out[token] += w * (fused @ W2) ----------------
// block: 128m x 128n, 32x32x16 MFMA, wave tile 64x64 (2x2 accs)
__global__ __launch_bounds__(256, 3) void gemm2_kernel(
    const bf16_t* __restrict__ fused,    // [PAIRS][I]
    const bf16_t* __restrict__ W2t,      // [E][H][I]
    const int* __restrict__ counts, const int* __restrict__ offsets,
    const int* __restrict__ blk_e, const int* __restrict__ blk_m0,
    const int* __restrict__ nblk,
    const int* __restrict__ pair_tok, const float* __restrict__ pair_w,
    float* __restrict__ out)             // [TOK][H]
{
    int by = blockIdx.y;
    if (by >= nblk[0]) return;
    int e = blk_e[by];
    int m0 = blk_m0[by];
    int cnt = counts[e];
    int off = offsets[e];
    int n0 = blockIdx.x * 128;           // h base

    __shared__ __align__(16) bf16_t la[128 * 64];
    __shared__ __align__(16) bf16_t lb[128 * 64];

    int tid = threadIdx.x;
    int w = tid >> 6, lane = tid & 63;
    int wm = w >> 1, wn = w & 1;
    int lrow = lane >> 3, lcol = lane & 7;
    int scol = lcol ^ lrow;

    const bf16_t* aptr[4];
    const bf16_t* bptr[4];
#pragma unroll
    for (int it = 0; it < 4; it++) {
        int r = it * 32 + w * 8 + lrow;
        int grow = m0 + r;
        if (grow >= cnt) grow = cnt - 1;
        aptr[it] = fused + (size_t)(off + grow) * I_ + scol * 8;
        bptr[it] = W2t + ((size_t)e * H_ + n0 + r) * I_ + scol * 8;
    }

    f32x16 acc[2][2];
#pragma unroll
    for (int a = 0; a < 2; a++)
#pragma unroll
        for (int b = 0; b < 2; b++) acc[a][b] = (f32x16)(0.f);

    int r32 = lane & 31;
    int khalf = lane >> 5;
    int rx = r32 & 7;

    for (int k0 = 0; k0 < I_; k0 += 64) {
#pragma unroll
        for (int it = 0; it < 4; it++) {
            gl_lds16(aptr[it] + k0, &la[(it * 32 + w * 8) * 64]);
            gl_lds16(bptr[it] + k0, &lb[(it * 32 + w * 8) * 64]);
        }
        __syncthreads();
#pragma unroll
        for (int t16 = 0; t16 < 4; t16++) {
            int seg = t16 * 2 + khalf;
            bf16x8 af[2], bfr[2];
#pragma unroll
            for (int ms = 0; ms < 2; ms++) {
                int row = wm * 64 + ms * 32 + r32;
                af[ms] = *(const bf16x8*)&la[row * 64 + (seg ^ rx) * 8];
            }
#pragma unroll
            for (int ns = 0; ns < 2; ns++) {
                int brow = wn * 64 + ns * 32 + r32;
                bfr[ns] = *(const bf16x8*)&lb[brow * 64 + (seg ^ rx) * 8];
            }
#pragma unroll
            for (int ms = 0; ms < 2; ms++)
#pragma unroll
                for (int ns = 0; ns < 2; ns++)
                    acc[ms][ns] = __builtin_amdgcn_mfma_f32_32x32x16_bf16(
                        af[ms], bfr[ns], acc[ms][ns], 0, 0, 0);
        }
        __syncthreads();
    }

#pragma unroll
    for (int ms = 0; ms < 2; ms++) {
#pragma unroll
        for (int reg = 0; reg < 16; reg++) {
            int rrow = (reg & 3) + 8 * (reg >> 2) + 4 * khalf;
            int grow = m0 + wm * 64 + ms * 32 + rrow;
            if (grow < cnt) {
                int slot = off + grow;
                int tok = pair_tok[slot];
                float wt = pair_w[slot];
#pragma unroll
                for (int ns = 0; ns < 2; ns++) {
                    int h = n0 + wn * 64 + ns * 32 + r32;
                    atomicAdd(&out[(size_t)tok * H_ + h], wt * acc[ms][ns][reg]);
                }
            }
        }
    }
}

// ---------------- host ----------------
extern "C" void kernel_launch(void* const* d_in, const int* in_sizes, int n_in,
                              void* d_out, int out_size, void* d_ws, size_t ws_size,
                              hipStream_t stream) {
    const float* x   = (const float*)d_in[0];
    const float* Wg  = (const float*)d_in[1];
    const float* W11 = (const float*)d_in[2];
    const float* W12 = (const float*)d_in[3];
    const float* W2  = (const float*)d_in[4];
    float* out = (float*)d_out;

    char* ws = (char*)d_ws;
    size_t o = 0;
    auto alloc = [&](size_t bytes) { size_t r = o; o = (o + bytes + 255) & ~(size_t)255; return r; };
    int*    counts   = (int*)(ws + alloc(E_ * 4));
    int*    offsets  = (int*)(ws + alloc(E_ * 4));
    int*    cursor   = (int*)(ws + alloc(E_ * 4));
    int*    blk_e    = (int*)(ws + alloc(MAXBLK * 4));
    int*    blk_m0   = (int*)(ws + alloc(MAXBLK * 4));
    int*    nblk     = (int*)(ws + alloc(4));
    int*    top2e    = (int*)(ws + alloc(TOK * 2 * 4));
    float*  top2w    = (float*)(ws + alloc(TOK * 2 * 4));
    int*    pair_tok = (int*)(ws + alloc(PAIRS * 4));
    float*  pair_w   = (float*)(ws + alloc(PAIRS * 4));
    bf16_t* xb       = (bf16_t*)(ws + alloc((size_t)TOK * H_ * 2));
    bf16_t* W11t     = (bf16_t*)(ws + alloc((size_t)E_ * I_ * H_ * 2));
    bf16_t* W12t     = (bf16_t*)(ws + alloc((size_t)E_ * I_ * H_ * 2));
    bf16_t* W2t      = (bf16_t*)(ws + alloc((size_t)E_ * I_ * H_ * 2));
    bf16_t* fusedbuf = (bf16_t*)(ws + alloc((size_t)PAIRS * I_ * 2));

    hipMemsetAsync(counts, 0, E_ * 4, stream);
    hipMemsetAsync(d_out, 0, (size_t)out_size * 4, stream);

    router_kernel<<<TOK / 4, 256, 0, stream>>>(x, Wg, top2e, top2w, counts);
    scan_kernel<<<1, 64, 0, stream>>>(counts, offsets, cursor, blk_e, blk_m0, nblk);
    fill_kernel<<<TOK / 256, 256, 0, stream>>>(top2e, top2w, cursor, pair_tok, pair_w);

    castx_kernel<<<(TOK * H_ / 4) / 256, 256, 0, stream>>>(x, xb);
    // W11/W12: [E][H][I] -> [E][I][H]
    transpose_cast_kernel<<<dim3(I_ / 64, H_ / 64, E_), 256, 0, stream>>>(W11, W11t, H_, I_);
    transpose_cast_kernel<<<dim3(I_ / 64, H_ / 64, E_), 256, 0, stream>>>(W12, W12t, H_, I_);
    // W2: [E][I][H] -> [E][H][I]
    transpose_cast_kernel<<<dim3(H_ / 64, I_ / 64, E_), 256, 0, stream>>>(W2, W2t, I_, H_);

    gemm1_kernel<<<dim3(I_ / 128, MAXBLK), 256, 0, stream>>>(
        xb, W11t, W12t, counts, offsets, blk_e, blk_m0, nblk, pair_tok, fusedbuf);
    gemm2_kernel<<<dim3(H_ / 128, MAXBLK), 256, 0, stream>>>(
        fusedbuf, W2t, counts, offsets, blk_e, blk_m0, nblk, pair_tok, pair_w, out);
}

// Round 4
// 527.548 us; speedup vs baseline: 1.1926x; 1.0258x over previous
//
#include <hip/hip_runtime.h>
#include <hip/hip_bf16.h>
#include <stdint.h>

#define B_ 2
#define S_ 2048
#define H_ 1024
#define I_ 2048
#define E_ 8
#define TOK (B_*S_)      // 4096 tokens
#define PAIRS (TOK*2)    // 8192 token-expert pairs
#define MAXBLK 80        // max sum_e ceil(cnt_e/128) = 64+7=71

typedef __bf16 bf16_t;
typedef __bf16 bf16x4 __attribute__((ext_vector_type(4)));
typedef __bf16 bf16x8 __attribute__((ext_vector_type(8)));
typedef float  f32x4  __attribute__((ext_vector_type(4)));
typedef float  f32x16 __attribute__((ext_vector_type(16)));

// async global->LDS, 16B per lane. LDS dest = wave-uniform base + lane*16.
__device__ __forceinline__ void gl_lds16(const bf16_t* g, bf16_t* l) {
    __builtin_amdgcn_global_load_lds(
        (const __attribute__((address_space(1))) unsigned int*)g,
        (__attribute__((address_space(3))) unsigned int*)l, 16, 0, 0);
}

// ---------------- Router ----------------
__global__ void router_kernel(const float* __restrict__ x, const float* __restrict__ Wg,
                              int* __restrict__ top2e, float* __restrict__ top2w,
                              int* __restrict__ counts) {
    int wave = threadIdx.x >> 6;
    int lane = threadIdx.x & 63;
    int t = blockIdx.x * 4 + wave;
    if (t >= TOK) return;
    float acc[E_];
#pragma unroll
    for (int e = 0; e < E_; e++) acc[e] = 0.f;
    const float* xrow = x + (size_t)t * H_;
    for (int j = 0; j < H_ / 64; j++) {
        int h = j * 64 + lane;
        float xv = xrow[h];
        const float4* wg = (const float4*)(Wg + (size_t)h * E_);
        float4 w0 = wg[0], w1 = wg[1];
        acc[0] += xv * w0.x; acc[1] += xv * w0.y; acc[2] += xv * w0.z; acc[3] += xv * w0.w;
        acc[4] += xv * w1.x; acc[5] += xv * w1.y; acc[6] += xv * w1.z; acc[7] += xv * w1.w;
    }
#pragma unroll
    for (int e = 0; e < E_; e++) {
#pragma unroll
        for (int m = 32; m >= 1; m >>= 1) acc[e] += __shfl_xor(acc[e], m, 64);
    }
    if (lane == 0) {
        float mx = acc[0];
        for (int e = 1; e < E_; e++) mx = fmaxf(mx, acc[e]);
        float p[E_]; float z = 0.f;
        for (int e = 0; e < E_; e++) { p[e] = __expf(acc[e] - mx); z += p[e]; }
        for (int e = 0; e < E_; e++) p[e] /= z;
        int i1 = 0; float p1 = p[0];
        for (int e = 1; e < E_; e++) if (p[e] > p1) { p1 = p[e]; i1 = e; }
        int i2 = -1; float p2 = -1.f;
        for (int e = 0; e < E_; e++) if (e != i1 && p[e] > p2) { p2 = p[e]; i2 = e; }
        float s = p1 + p2 + 1e-8f;
        top2e[t * 2]     = i1; top2e[t * 2 + 1] = i2;
        top2w[t * 2]     = p1 / s; top2w[t * 2 + 1] = p2 / s;
        atomicAdd(&counts[i1], 1);
        atomicAdd(&counts[i2], 1);
    }
}

// scan + build block schedule (expert, m0) for 128-row m-tiles
__global__ void scan_kernel(const int* __restrict__ counts, int* __restrict__ offsets,
                            int* __restrict__ cursor, int* __restrict__ blk_e,
                            int* __restrict__ blk_m0, int* __restrict__ nblk) {
    if (threadIdx.x == 0 && blockIdx.x == 0) {
        int run = 0, b = 0;
        for (int e = 0; e < E_; e++) {
            offsets[e] = run; cursor[e] = run;
            int c = counts[e];
            for (int m0 = 0; m0 < c; m0 += 128) { blk_e[b] = e; blk_m0[b] = m0; b++; }
            run += c;
        }
        nblk[0] = b;
    }
}

// also writes inverse map: inv[t*2+k] = slot of (t,k) in pair list
__global__ void fill_kernel(const int* __restrict__ top2e,
                            int* __restrict__ cursor, int* __restrict__ pair_tok,
                            int* __restrict__ inv) {
    int t = blockIdx.x * blockDim.x + threadIdx.x;
    if (t >= TOK) return;
#pragma unroll
    for (int k = 0; k < 2; k++) {
        int e = top2e[t * 2 + k];
        int pos = atomicAdd(&cursor[e], 1);
        pair_tok[pos] = t;
        inv[t * 2 + k] = pos;
    }
}

// ---------------- casts ----------------
__global__ void castx_kernel(const float* __restrict__ x, bf16_t* __restrict__ xb) {
    size_t i = ((size_t)blockIdx.x * blockDim.x + threadIdx.x) * 4;
    float4 v = *(const float4*)(x + i);
    bf16x4 o = { (bf16_t)v.x, (bf16_t)v.y, (bf16_t)v.z, (bf16_t)v.w };
    *(bf16x4*)(xb + i) = o;
}

// src: [E][R][C] fp32 -> dst: [E][C][R] bf16.
// Tile: 64 src-rows x 128 src-cols. Output: 128 rows x 64 bf16 = full 128B/row,
// written as 8 lanes x 16B contiguous per out-row (full-line writes).
__global__ __launch_bounds__(256) void transpose_cast_kernel(
    const float* __restrict__ src, bf16_t* __restrict__ dst, int R, int C) {
    __shared__ float tile[64][129];
    int e = blockIdx.z;
    const float* s = src + (size_t)e * R * C;
    bf16_t* d = dst + (size_t)e * R * C;
    int c0 = blockIdx.x * 128, r0 = blockIdx.y * 64;
    int t = threadIdx.x;
    // load: 64 rows x 128 cols, float4 per lane, 8 iters
#pragma unroll
    for (int j = 0; j < 8; j++) {
        int flat = j * 256 + t;          // 0..2047
        int r = flat >> 5;               // 0..63
        int c4 = (flat & 31) * 4;        // 0..124
        float4 v = *(const float4*)(s + (size_t)(r0 + r) * C + c0 + c4);
        tile[r][c4 + 0] = v.x;
        tile[r][c4 + 1] = v.y;
        tile[r][c4 + 2] = v.z;
        tile[r][c4 + 3] = v.w;
    }
    __syncthreads();
    // store: 128 out-rows x 64 elems; 8 lanes cover one out-row (128B line)
#pragma unroll
    for (int j = 0; j < 4; j++) {
        int flat = j * 256 + t;          // 0..1023
        int orow = flat >> 3;            // 0..127 (src col)
        int seg  = (flat & 7) * 8;       // 0..56 (src row base)
        bf16x8 v;
#pragma unroll
        for (int k = 0; k < 8; k++) v[k] = (bf16_t)tile[seg + k][orow];
        *(bf16x8*)(d + (size_t)(c0 + orow) * R + r0 + seg) = v;
    }
}

// ---------------- GEMM1: fused = SiLU(x@W11) * (x@W12) ----------------
// block: 128 m-rows x 128 i-cols (gate+value => N_eff=256), 32x32x16 MFMA.
// 4 waves 2x2; wave tile 64m x (64 gate + 64 value).
// LDS XOR-swizzle: physical 16B slot s^(row&7) holds logical seg s.
__global__ __launch_bounds__(256, 2) void gemm1_kernel(
    const bf16_t* __restrict__ xb,       // [TOK][H]
    const bf16_t* __restrict__ W11t,     // [E][I][H]
    const bf16_t* __restrict__ W12t,     // [E][I][H]
    const int* __restrict__ counts, const int* __restrict__ offsets,
    const int* __restrict__ blk_e, const int* __restrict__ blk_m0,
    const int* __restrict__ nblk,
    const int* __restrict__ pair_tok,
    bf16_t* __restrict__ fused)          // [PAIRS][I]
{
    int by = blockIdx.y;
    if (by >= nblk[0]) return;
    int e = blk_e[by];
    int m0 = blk_m0[by];
    int cnt = counts[e];
    int off = offsets[e];
    int n0 = blockIdx.x * 128;           // i-col base

    __shared__ __align__(16) bf16_t la[128 * 64];   // 16 KB
    __shared__ __align__(16) bf16_t lb[256 * 64];   // 32 KB: rows 0..127 gate, 128..255 value

    int tid = threadIdx.x;
    int w = tid >> 6, lane = tid & 63;
    int wm = w >> 1, wn = w & 1;
    int lrow = lane >> 3, lcol = lane & 7;
    int scol = lcol ^ lrow;              // swizzled source segment

    const bf16_t* aptr4[4];
    const bf16_t* bptr[8];
#pragma unroll
    for (int it = 0; it < 4; it++) {
        int r = it * 32 + w * 8 + lrow;
        int grow = m0 + r;
        int tok = pair_tok[off + (grow < cnt ? grow : 0)];
        aptr4[it] = xb + (size_t)tok * H_ + scol * 8;
    }
#pragma unroll
    for (int it = 0; it < 8; it++) {
        int r = it * 32 + w * 8 + lrow;  // 0..255
        const bf16_t* base = (r < 128)
            ? (W11t + ((size_t)e * I_ + n0 + r) * H_)
            : (W12t + ((size_t)e * I_ + n0 + (r - 128)) * H_);
        bptr[it] = base + scol * 8;
    }

    f32x16 acc[2][4];                    // [ms][ns]: ns 0,1 gate; 2,3 value
#pragma unroll
    for (int a = 0; a < 2; a++)
#pragma unroll
        for (int b = 0; b < 4; b++) acc[a][b] = (f32x16)(0.f);

    int r32 = lane & 31;
    int khalf = lane >> 5;               // 0/1 -> k-seg offset
    int rx = r32 & 7;

    for (int k0 = 0; k0 < H_; k0 += 64) {
#pragma unroll
        for (int it = 0; it < 4; it++)
            gl_lds16(aptr4[it] + k0, &la[(it * 32 + w * 8) * 64]);
#pragma unroll
        for (int it = 0; it < 8; it++)
            gl_lds16(bptr[it] + k0, &lb[(it * 32 + w * 8) * 64]);
        __syncthreads();
#pragma unroll
        for (int t16 = 0; t16 < 4; t16++) {
            int seg = t16 * 2 + khalf;
            bf16x8 af[2], bfr[4];
#pragma unroll
            for (int ms = 0; ms < 2; ms++) {
                int row = wm * 64 + ms * 32 + r32;
                af[ms] = *(const bf16x8*)&la[row * 64 + (seg ^ rx) * 8];
            }
#pragma unroll
            for (int ns = 0; ns < 2; ns++) {
                int browg = wn * 64 + ns * 32 + r32;
                bfr[ns]     = *(const bf16x8*)&lb[browg * 64 + (seg ^ rx) * 8];
                bfr[ns + 2] = *(const bf16x8*)&lb[(browg + 128) * 64 + (seg ^ rx) * 8];
            }
#pragma unroll
            for (int ms = 0; ms < 2; ms++)
#pragma unroll
                for (int ns = 0; ns < 4; ns++)
                    acc[ms][ns] = __builtin_amdgcn_mfma_f32_32x32x16_bf16(
                        af[ms], bfr[ns], acc[ms][ns], 0, 0, 0);
        }
        __syncthreads();
    }

    // C/D 32x32 layout: col=lane&31, row=(reg&3)+8*(reg>>2)+4*(lane>>5)
#pragma unroll
    for (int ms = 0; ms < 2; ms++) {
#pragma unroll
        for (int ns = 0; ns < 2; ns++) {
            int i = n0 + wn * 64 + ns * 32 + r32;
#pragma unroll
            for (int reg = 0; reg < 16; reg++) {
                int rrow = (reg & 3) + 8 * (reg >> 2) + 4 * khalf;
                int grow = m0 + wm * 64 + ms * 32 + rrow;
                if (grow < cnt) {
                    float g = acc[ms][ns][reg];
                    float v = acc[ms][ns + 2][reg];
                    float f = g * v / (1.f + __expf(-g));
                    fused[(size_t)(off + grow) * I_ + i] = (bf16_t)f;
                }
            }
        }
    }
}

// ---------------- GEMM2: y[slot] = fused[slot] @ W2 (no atomics) ----------------
// block: 128m x 128n, 32x32x16 MFMA, wave tile 64x64 (2x2 accs)
__global__ __launch_bounds__(256, 3) void gemm2_kernel(
    const bf16_t* __restrict__ fused,    // [PAIRS][I]
    const bf16_t* __restrict__ W2t,      // [E][H][I]
    const int* __restrict__ counts, const int* __restrict__ offsets,
    const int* __restrict__ blk_e, const int* __restrict__ blk_m0,
    const int* __restrict__ nblk,
    float* __restrict__ y)               // [PAIRS][H]
{
    int by = blockIdx.y;
    if (by >= nblk[0]) return;
    int e = blk_e[by];
    int m0 = blk_m0[by];
    int cnt = counts[e];
    int off = offsets[e];
    int n0 = blockIdx.x * 128;           // h base

    __shared__ __align__(16) bf16_t la[128 * 64];
    __shared__ __align__(16) bf16_t lb[128 * 64];

    int tid = threadIdx.x;
    int w = tid >> 6, lane = tid & 63;
    int wm = w >> 1, wn = w & 1;
    int lrow = lane >> 3, lcol = lane & 7;
    int scol = lcol ^ lrow;

    const bf16_t* aptr[4];
    const bf16_t* bptr[4];
#pragma unroll
    for (int it = 0; it < 4; it++) {
        int r = it * 32 + w * 8 + lrow;
        int grow = m0 + r;
        if (grow >= cnt) grow = cnt - 1;
        aptr[it] = fused + (size_t)(off + grow) * I_ + scol * 8;
        bptr[it] = W2t + ((size_t)e * H_ + n0 + r) * I_ + scol * 8;
    }

    f32x16 acc[2][2];
#pragma unroll
    for (int a = 0; a < 2; a++)
#pragma unroll
        for (int b = 0; b < 2; b++) acc[a][b] = (f32x16)(0.f);

    int r32 = lane & 31;
    int khalf = lane >> 5;
    int rx = r32 & 7;

    for (int k0 = 0; k0 < I_; k0 += 64) {
#pragma unroll
        for (int it = 0; it < 4; it++) {
            gl_lds16(aptr[it] + k0, &la[(it * 32 + w * 8) * 64]);
            gl_lds16(bptr[it] + k0, &lb[(it * 32 + w * 8) * 64]);
        }
        __syncthreads();
#pragma unroll
        for (int t16 = 0; t16 < 4; t16++) {
            int seg = t16 * 2 + khalf;
            bf16x8 af[2], bfr[2];
#pragma unroll
            for (int ms = 0; ms < 2; ms++) {
                int row = wm * 64 + ms * 32 + r32;
                af[ms] = *(const bf16x8*)&la[row * 64 + (seg ^ rx) * 8];
            }
#pragma unroll
            for (int ns = 0; ns < 2; ns++) {
                int brow = wn * 64 + ns * 32 + r32;
                bfr[ns] = *(const bf16x8*)&lb[brow * 64 + (seg ^ rx) * 8];
            }
#pragma unroll
            for (int ms = 0; ms < 2; ms++)
#pragma unroll
                for (int ns = 0; ns < 2; ns++)
                    acc[ms][ns] = __builtin_amdgcn_mfma_f32_32x32x16_bf16(
                        af[ms], bfr[ns], acc[ms][ns], 0, 0, 0);
        }
        __syncthreads();
    }

#pragma unroll
    for (int ms = 0; ms < 2; ms++) {
#pragma unroll
        for (int reg = 0; reg < 16; reg++) {
            int rrow = (reg & 3) + 8 * (reg >> 2) + 4 * khalf;
            int grow = m0 + wm * 64 + ms * 32 + rrow;
            if (grow < cnt) {
                int slot = off + grow;
#pragma unroll
                for (int ns = 0; ns < 2; ns++) {
                    int h = n0 + wn * 64 + ns * 32 + r32;
                    y[(size_t)slot * H_ + h] = acc[ms][ns][reg];
                }
            }
        }
    }
}

// ---------------- combine: out[t] = w1*y[s1] + w2*y[s2] ----------------
__global__ __launch_bounds__(256) void combine_kernel(
    const float* __restrict__ y, const int* __restrict__ inv,
    const float* __restrict__ top2w, float* __restrict__ out) {
    int t = blockIdx.x;
    int h = threadIdx.x * 4;
    int s1 = inv[t * 2], s2 = inv[t * 2 + 1];
    float w1 = top2w[t * 2], w2 = top2w[t * 2 + 1];
    f32x4 a = *(const f32x4*)(y + (size_t)s1 * H_ + h);
    f32x4 b = *(const f32x4*)(y + (size_t)s2 * H_ + h);
    f32x4 r = a * w1 + b * w2;
    *(f32x4*)(out + (size_t)t * H_ + h) = r;
}

// ---------------- host ----------------
extern "C" void kernel_launch(void* const* d_in, const int* in_sizes, int n_in,
                              void* d_out, int out_size, void* d_ws, size_t ws_size,
                              hipStream_t stream) {
    const float* x   = (const float*)d_in[0];
    const float* Wg  = (const float*)d_in[1];
    const float* W11 = (const float*)d_in[2];
    const float* W12 = (const float*)d_in[3];
    const float* W2  = (const float*)d_in[4];
    float* out = (float*)d_out;

    char* ws = (char*)d_ws;
    size_t o = 0;
    auto alloc = [&](size_t bytes) { size_t r = o; o = (o + bytes + 255) & ~(size_t)255; return r; };
    int*    counts   = (int*)(ws + alloc(E_ * 4));
    int*    offsets  = (int*)(ws + alloc(E_ * 4));
    int*    cursor   = (int*)(ws + alloc(E_ * 4));
    int*    blk_e    = (int*)(ws + alloc(MAXBLK * 4));
    int*    blk_m0   = (int*)(ws + alloc(MAXBLK * 4));
    int*    nblk     = (int*)(ws + alloc(4));
    int*    top2e    = (int*)(ws + alloc(TOK * 2 * 4));
    float*  top2w    = (float*)(ws + alloc(TOK * 2 * 4));
    int*    pair_tok = (int*)(ws + alloc(PAIRS * 4));
    int*    inv      = (int*)(ws + alloc(TOK * 2 * 4));
    bf16_t* xb       = (bf16_t*)(ws + alloc((size_t)TOK * H_ * 2));
    bf16_t* W11t     = (bf16_t*)(ws + alloc((size_t)E_ * I_ * H_ * 2));
    bf16_t* W12t     = (bf16_t*)(ws + alloc((size_t)E_ * I_ * H_ * 2));
    bf16_t* W2t      = (bf16_t*)(ws + alloc((size_t)E_ * I_ * H_ * 2));
    bf16_t* fusedbuf = (bf16_t*)(ws + alloc((size_t)PAIRS * I_ * 2));
    float*  ybuf     = (float*)(ws + alloc((size_t)PAIRS * H_ * 4));

    hipMemsetAsync(counts, 0, E_ * 4, stream);

    router_kernel<<<TOK / 4, 256, 0, stream>>>(x, Wg, top2e, top2w, counts);
    scan_kernel<<<1, 64, 0, stream>>>(counts, offsets, cursor, blk_e, blk_m0, nblk);
    fill_kernel<<<TOK / 256, 256, 0, stream>>>(top2e, cursor, pair_tok, inv);

    castx_kernel<<<(TOK * H_ / 4) / 256, 256, 0, stream>>>(x, xb);
    // W11/W12: [E][H][I] -> [E][I][H]   (R=H, C=I)
    transpose_cast_kernel<<<dim3(I_ / 128, H_ / 64, E_), 256, 0, stream>>>(W11, W11t, H_, I_);
    transpose_cast_kernel<<<dim3(I_ / 128, H_ / 64, E_), 256, 0, stream>>>(W12, W12t, H_, I_);
    // W2: [E][I][H] -> [E][H][I]        (R=I, C=H)
    transpose_cast_kernel<<<dim3(H_ / 128, I_ / 64, E_), 256, 0, stream>>>(W2, W2t, I_, H_);

    gemm1_kernel<<<dim3(I_ / 128, MAXBLK), 256, 0, stream>>>(
        xb, W11t, W12t, counts, offsets, blk_e, blk_m0, nblk, pair_tok, fusedbuf);
    gemm2_kernel<<<dim3(H_ / 128, MAXBLK), 256, 0, stream>>>(
        fusedbuf, W2t, counts, offsets, blk_e, blk_m0, nblk, ybuf);
    combine_kernel<<<TOK, 256, 0, stream>>>(ybuf, inv, top2w, out);
}

// Round 5
// 497.065 us; speedup vs baseline: 1.2658x; 1.0613x over previous
//
#include <hip/hip_runtime.h>
#include <hip/hip_bf16.h>
#include <stdint.h>

#define B_ 2
#define S_ 2048
#define H_ 1024
#define I_ 2048
#define E_ 8
#define TOK (B_*S_)      // 4096 tokens
#define PAIRS (TOK*2)    // 8192 token-expert pairs
#define MAXBLK 80        // max sum_e ceil(cnt_e/128) = 64+7=71

typedef __bf16 bf16_t;
typedef __bf16 bf16x4 __attribute__((ext_vector_type(4)));
typedef __bf16 bf16x8 __attribute__((ext_vector_type(8)));
typedef float  f32x4  __attribute__((ext_vector_type(4)));
typedef float  f32x16 __attribute__((ext_vector_type(16)));

// async global->LDS, 16B per lane. LDS dest = wave-uniform base + lane*16.
__device__ __forceinline__ void gl_lds16(const bf16_t* g, bf16_t* l) {
    __builtin_amdgcn_global_load_lds(
        (const __attribute__((address_space(1))) unsigned int*)g,
        (__attribute__((address_space(3))) unsigned int*)l, 16, 0, 0);
}

// ---------------- Router (+ x -> bf16 cast fused) ----------------
__global__ void router_kernel(const float* __restrict__ x, const float* __restrict__ Wg,
                              int* __restrict__ top2e, float* __restrict__ top2w,
                              int* __restrict__ counts, bf16_t* __restrict__ xb) {
    int wave = threadIdx.x >> 6;
    int lane = threadIdx.x & 63;
    int t = blockIdx.x * 4 + wave;
    if (t >= TOK) return;
    float acc[E_];
#pragma unroll
    for (int e = 0; e < E_; e++) acc[e] = 0.f;
    const float* xrow = x + (size_t)t * H_;
    for (int j = 0; j < H_ / 64; j++) {
        int h = j * 64 + lane;
        float xv = xrow[h];
        const float4* wg = (const float4*)(Wg + (size_t)h * E_);
        float4 w0 = wg[0], w1 = wg[1];
        acc[0] += xv * w0.x; acc[1] += xv * w0.y; acc[2] += xv * w0.z; acc[3] += xv * w0.w;
        acc[4] += xv * w1.x; acc[5] += xv * w1.y; acc[6] += xv * w1.z; acc[7] += xv * w1.w;
    }
    // fused cast: write this token's bf16 row (re-read hits L1/L2)
#pragma unroll
    for (int part = 0; part < 2; part++) {
        int idx = part * 512 + lane * 8;
        float4 v0 = *(const float4*)(xrow + idx);
        float4 v1 = *(const float4*)(xrow + idx + 4);
        bf16x8 ov = { (bf16_t)v0.x, (bf16_t)v0.y, (bf16_t)v0.z, (bf16_t)v0.w,
                      (bf16_t)v1.x, (bf16_t)v1.y, (bf16_t)v1.z, (bf16_t)v1.w };
        *(bf16x8*)(xb + (size_t)t * H_ + idx) = ov;
    }
#pragma unroll
    for (int e = 0; e < E_; e++) {
#pragma unroll
        for (int m = 32; m >= 1; m >>= 1) acc[e] += __shfl_xor(acc[e], m, 64);
    }
    if (lane == 0) {
        float mx = acc[0];
        for (int e = 1; e < E_; e++) mx = fmaxf(mx, acc[e]);
        float p[E_]; float z = 0.f;
        for (int e = 0; e < E_; e++) { p[e] = __expf(acc[e] - mx); z += p[e]; }
        for (int e = 0; e < E_; e++) p[e] /= z;
        int i1 = 0; float p1 = p[0];
        for (int e = 1; e < E_; e++) if (p[e] > p1) { p1 = p[e]; i1 = e; }
        int i2 = -1; float p2 = -1.f;
        for (int e = 0; e < E_; e++) if (e != i1 && p[e] > p2) { p2 = p[e]; i2 = e; }
        float s = p1 + p2 + 1e-8f;
        top2e[t * 2]     = i1; top2e[t * 2 + 1] = i2;
        top2w[t * 2]     = p1 / s; top2w[t * 2 + 1] = p2 / s;
        atomicAdd(&counts[i1], 1);
        atomicAdd(&counts[i2], 1);
    }
}

// ---------------- scan + fill in one block (LDS cursors) ----------------
__global__ __launch_bounds__(256) void scanfill_kernel(
    const int* __restrict__ counts, int* __restrict__ offsets,
    int* __restrict__ blk_e, int* __restrict__ blk_m0, int* __restrict__ nblk,
    const int* __restrict__ top2e, int* __restrict__ pair_tok, int* __restrict__ inv) {
    __shared__ int s_cur[E_];
    if (threadIdx.x == 0) {
        int run = 0, b = 0;
        for (int e = 0; e < E_; e++) {
            offsets[e] = run; s_cur[e] = run;
            int c = counts[e];
            for (int m0 = 0; m0 < c; m0 += 128) { blk_e[b] = e; blk_m0[b] = m0; b++; }
            run += c;
        }
        nblk[0] = b;
    }
    __syncthreads();
    for (int p = threadIdx.x; p < PAIRS; p += 256) {
        int e = top2e[p];
        int pos = atomicAdd(&s_cur[e], 1);
        pair_tok[pos] = p >> 1;
        inv[p] = pos;
    }
}

// ---------------- merged weight transpose-cast ----------------
// z = w*E+e, w in {0:W11, 1:W12, 2:W2}. src [R][C] fp32 -> dst [C][R] bf16.
__global__ __launch_bounds__(256) void wtrans_kernel(
    const float* __restrict__ W11, const float* __restrict__ W12,
    const float* __restrict__ W2,
    bf16_t* __restrict__ W11t, bf16_t* __restrict__ W12t, bf16_t* __restrict__ W2t) {
    __shared__ float tile[64][129];
    int z = blockIdx.y;
    int wsel = z >> 3, e = z & 7;
    const float* sbase; bf16_t* dbase; int R, C, tx, ty;
    if (wsel == 0)      { sbase = W11; dbase = W11t; R = H_; C = I_; }
    else if (wsel == 1) { sbase = W12; dbase = W12t; R = H_; C = I_; }
    else                { sbase = W2;  dbase = W2t;  R = I_; C = H_; }
    if (wsel < 2) { tx = blockIdx.x & 15; ty = blockIdx.x >> 4; }   // 16 x 16
    else          { tx = blockIdx.x & 7;  ty = blockIdx.x >> 3; }   // 8 x 32
    const float* s = sbase + (size_t)e * R * C;
    bf16_t* d = dbase + (size_t)e * R * C;
    int c0 = tx * 128, r0 = ty * 64;
    int t = threadIdx.x;
#pragma unroll
    for (int j = 0; j < 8; j++) {
        int flat = j * 256 + t;          // 0..2047
        int r = flat >> 5;               // 0..63
        int c4 = (flat & 31) * 4;        // 0..124
        float4 v = *(const float4*)(s + (size_t)(r0 + r) * C + c0 + c4);
        tile[r][c4 + 0] = v.x;
        tile[r][c4 + 1] = v.y;
        tile[r][c4 + 2] = v.z;
        tile[r][c4 + 3] = v.w;
    }
    __syncthreads();
#pragma unroll
    for (int j = 0; j < 4; j++) {
        int flat = j * 256 + t;          // 0..1023
        int orow = flat >> 3;            // 0..127 (src col)
        int seg  = (flat & 7) * 8;       // 0..56 (src row base)
        bf16x8 v;
#pragma unroll
        for (int k = 0; k < 8; k++) v[k] = (bf16_t)tile[seg + k][orow];
        *(bf16x8*)(d + (size_t)(c0 + orow) * R + r0 + seg) = v;
    }
}

// ---------------- GEMM1: fused = SiLU(x@W11) * (x@W12) ----------------
// block: 128m x 128i (gate+value => 256 B-rows), 32x32x16 MFMA, 4 waves 2x2.
// LDS XOR-swizzle: physical 16B slot s^(row&7) holds logical seg s.
__global__ __launch_bounds__(256, 2) void gemm1_kernel(
    const bf16_t* __restrict__ xb,       // [TOK][H]
    const bf16_t* __restrict__ W11t,     // [E][I][H]
    const bf16_t* __restrict__ W12t,     // [E][I][H]
    const int* __restrict__ counts, const int* __restrict__ offsets,
    const int* __restrict__ blk_e, const int* __restrict__ blk_m0,
    const int* __restrict__ nblk,
    const int* __restrict__ pair_tok,
    bf16_t* __restrict__ fused)          // [PAIRS][I]
{
    int by = blockIdx.y;
    if (by >= nblk[0]) return;
    int e = blk_e[by];
    int m0 = blk_m0[by];
    int cnt = counts[e];
    int off = offsets[e];
    int n0 = blockIdx.x * 128;           // i-col base

    __shared__ __align__(16) bf16_t la[128 * 64];   // 16 KB
    __shared__ __align__(16) bf16_t lb[256 * 64];   // 32 KB

    int tid = threadIdx.x;
    int w = tid >> 6, lane = tid & 63;
    int wm = w >> 1, wn = w & 1;
    int lrow = lane >> 3, lcol = lane & 7;
    int scol = lcol ^ lrow;

    const bf16_t* aptr4[4];
    const bf16_t* bptr[8];
#pragma unroll
    for (int it = 0; it < 4; it++) {
        int r = it * 32 + w * 8 + lrow;
        int grow = m0 + r;
        int tok = pair_tok[off + (grow < cnt ? grow : 0)];
        aptr4[it] = xb + (size_t)tok * H_ + scol * 8;
    }
#pragma unroll
    for (int it = 0; it < 8; it++) {
        int r = it * 32 + w * 8 + lrow;  // 0..255
        const bf16_t* base = (r < 128)
            ? (W11t + ((size_t)e * I_ + n0 + r) * H_)
            : (W12t + ((size_t)e * I_ + n0 + (r - 128)) * H_);
        bptr[it] = base + scol * 8;
    }

    f32x16 acc[2][4];
#pragma unroll
    for (int a = 0; a < 2; a++)
#pragma unroll
        for (int b = 0; b < 4; b++) acc[a][b] = (f32x16)(0.f);

    int r32 = lane & 31;
    int khalf = lane >> 5;
    int rx = r32 & 7;

    for (int k0 = 0; k0 < H_; k0 += 64) {
#pragma unroll
        for (int it = 0; it < 4; it++)
            gl_lds16(aptr4[it] + k0, &la[(it * 32 + w * 8) * 64]);
#pragma unroll
        for (int it = 0; it < 8; it++)
            gl_lds16(bptr[it] + k0, &lb[(it * 32 + w * 8) * 64]);
        __syncthreads();
#pragma unroll
        for (int t16 = 0; t16 < 4; t16++) {
            int seg = t16 * 2 + khalf;
            bf16x8 af[2], bfr[4];
#pragma unroll
            for (int ms = 0; ms < 2; ms++) {
                int row = wm * 64 + ms * 32 + r32;
                af[ms] = *(const bf16x8*)&la[row * 64 + (seg ^ rx) * 8];
            }
#pragma unroll
            for (int ns = 0; ns < 2; ns++) {
                int browg = wn * 64 + ns * 32 + r32;
                bfr[ns]     = *(const bf16x8*)&lb[browg * 64 + (seg ^ rx) * 8];
                bfr[ns + 2] = *(const bf16x8*)&lb[(browg + 128) * 64 + (seg ^ rx) * 8];
            }
#pragma unroll
            for (int ms = 0; ms < 2; ms++)
#pragma unroll
                for (int ns = 0; ns < 4; ns++)
                    acc[ms][ns] = __builtin_amdgcn_mfma_f32_32x32x16_bf16(
                        af[ms], bfr[ns], acc[ms][ns], 0, 0, 0);
        }
        __syncthreads();
    }

    // C/D 32x32 layout: col=lane&31, row=(reg&3)+8*(reg>>2)+4*(lane>>5)
#pragma unroll
    for (int ms = 0; ms < 2; ms++) {
#pragma unroll
        for (int ns = 0; ns < 2; ns++) {
            int i = n0 + wn * 64 + ns * 32 + r32;
#pragma unroll
            for (int reg = 0; reg < 16; reg++) {
                int rrow = (reg & 3) + 8 * (reg >> 2) + 4 * khalf;
                int grow = m0 + wm * 64 + ms * 32 + rrow;
                if (grow < cnt) {
                    float g = acc[ms][ns][reg];
                    float v = acc[ms][ns + 2][reg];
                    float f = g * v / (1.f + __expf(-g));
                    fused[(size_t)(off + grow) * I_ + i] = (bf16_t)f;
                }
            }
        }
    }
}

// ---------------- GEMM2: y[slot] = fused[slot] @ W2, bf16 out ----------------
__global__ __launch_bounds__(256, 3) void gemm2_kernel(
    const bf16_t* __restrict__ fused,    // [PAIRS][I]
    const bf16_t* __restrict__ W2t,      // [E][H][I]
    const int* __restrict__ counts, const int* __restrict__ offsets,
    const int* __restrict__ blk_e, const int* __restrict__ blk_m0,
    const int* __restrict__ nblk,
    bf16_t* __restrict__ y)              // [PAIRS][H]
{
    int by = blockIdx.y;
    if (by >= nblk[0]) return;
    int e = blk_e[by];
    int m0 = blk_m0[by];
    int cnt = counts[e];
    int off = offsets[e];
    int n0 = blockIdx.x * 128;

    __shared__ __align__(16) bf16_t la[128 * 64];
    __shared__ __align__(16) bf16_t lb[128 * 64];

    int tid = threadIdx.x;
    int w = tid >> 6, lane = tid & 63;
    int wm = w >> 1, wn = w & 1;
    int lrow = lane >> 3, lcol = lane & 7;
    int scol = lcol ^ lrow;

    const bf16_t* aptr[4];
    const bf16_t* bptr[4];
#pragma unroll
    for (int it = 0; it < 4; it++) {
        int r = it * 32 + w * 8 + lrow;
        int grow = m0 + r;
        if (grow >= cnt) grow = cnt - 1;
        aptr[it] = fused + (size_t)(off + grow) * I_ + scol * 8;
        bptr[it] = W2t + ((size_t)e * H_ + n0 + r) * I_ + scol * 8;
    }

    f32x16 acc[2][2];
#pragma unroll
    for (int a = 0; a < 2; a++)
#pragma unroll
        for (int b = 0; b < 2; b++) acc[a][b] = (f32x16)(0.f);

    int r32 = lane & 31;
    int khalf = lane >> 5;
    int rx = r32 & 7;

    for (int k0 = 0; k0 < I_; k0 += 64) {
#pragma unroll
        for (int it = 0; it < 4; it++) {
            gl_lds16(aptr[it] + k0, &la[(it * 32 + w * 8) * 64]);
            gl_lds16(bptr[it] + k0, &lb[(it * 32 + w * 8) * 64]);
        }
        __syncthreads();
#pragma unroll
        for (int t16 = 0; t16 < 4; t16++) {
            int seg = t16 * 2 + khalf;
            bf16x8 af[2], bfr[2];
#pragma unroll
            for (int ms = 0; ms < 2; ms++) {
                int row = wm * 64 + ms * 32 + r32;
                af[ms] = *(const bf16x8*)&la[row * 64 + (seg ^ rx) * 8];
            }
#pragma unroll
            for (int ns = 0; ns < 2; ns++) {
                int brow = wn * 64 + ns * 32 + r32;
                bfr[ns] = *(const bf16x8*)&lb[brow * 64 + (seg ^ rx) * 8];
            }
#pragma unroll
            for (int ms = 0; ms < 2; ms++)
#pragma unroll
                for (int ns = 0; ns < 2; ns++)
                    acc[ms][ns] = __builtin_amdgcn_mfma_f32_32x32x16_bf16(
                        af[ms], bfr[ns], acc[ms][ns], 0, 0, 0);
        }
        __syncthreads();
    }

#pragma unroll
    for (int ms = 0; ms < 2; ms++) {
#pragma unroll
        for (int reg = 0; reg < 16; reg++) {
            int rrow = (reg & 3) + 8 * (reg >> 2) + 4 * khalf;
            int grow = m0 + wm * 64 + ms * 32 + rrow;
            if (grow < cnt) {
                int slot = off + grow;
#pragma unroll
                for (int ns = 0; ns < 2; ns++) {
                    int h = n0 + wn * 64 + ns * 32 + r32;
                    y[(size_t)slot * H_ + h] = (bf16_t)acc[ms][ns][reg];
                }
            }
        }
    }
}

// ---------------- combine: out[t] = w1*y[s1] + w2*y[s2] ----------------
__global__ __launch_bounds__(256) void combine_kernel(
    const bf16_t* __restrict__ y, const int* __restrict__ inv,
    const float* __restrict__ top2w, float* __restrict__ out) {
    int t = blockIdx.x;
    int h = threadIdx.x * 4;
    int s1 = inv[t * 2], s2 = inv[t * 2 + 1];
    float w1 = top2w[t * 2], w2 = top2w[t * 2 + 1];
    bf16x4 a = *(const bf16x4*)(y + (size_t)s1 * H_ + h);
    bf16x4 b = *(const bf16x4*)(y + (size_t)s2 * H_ + h);
    f32x4 r;
#pragma unroll
    for (int k = 0; k < 4; k++) r[k] = w1 * (float)a[k] + w2 * (float)b[k];
    *(f32x4*)(out + (size_t)t * H_ + h) = r;
}

// ---------------- host ----------------
extern "C" void kernel_launch(void* const* d_in, const int* in_sizes, int n_in,
                              void* d_out, int out_size, void* d_ws, size_t ws_size,
                              hipStream_t stream) {
    const float* x   = (const float*)d_in[0];
    const float* Wg  = (const float*)d_in[1];
    const float* W11 = (const float*)d_in[2];
    const float* W12 = (const float*)d_in[3];
    const float* W2  = (const float*)d_in[4];
    float* out = (float*)d_out;

    char* ws = (char*)d_ws;
    size_t o = 0;
    auto alloc = [&](size_t bytes) { size_t r = o; o = (o + bytes + 255) & ~(size_t)255; return r; };
    int*    counts   = (int*)(ws + alloc(E_ * 4));
    int*    offsets  = (int*)(ws + alloc(E_ * 4));
    int*    blk_e    = (int*)(ws + alloc(MAXBLK * 4));
    int*    blk_m0   = (int*)(ws + alloc(MAXBLK * 4));
    int*    nblk     = (int*)(ws + alloc(4));
    int*    top2e    = (int*)(ws + alloc(TOK * 2 * 4));
    float*  top2w    = (float*)(ws + alloc(TOK * 2 * 4));
    int*    pair_tok = (int*)(ws + alloc(PAIRS * 4));
    int*    inv      = (int*)(ws + alloc(TOK * 2 * 4));
    bf16_t* xb       = (bf16_t*)(ws + alloc((size_t)TOK * H_ * 2));
    bf16_t* W11t     = (bf16_t*)(ws + alloc((size_t)E_ * I_ * H_ * 2));
    bf16_t* W12t     = (bf16_t*)(ws + alloc((size_t)E_ * I_ * H_ * 2));
    bf16_t* W2t      = (bf16_t*)(ws + alloc((size_t)E_ * I_ * H_ * 2));
    bf16_t* fusedbuf = (bf16_t*)(ws + alloc((size_t)PAIRS * I_ * 2));
    bf16_t* ybuf     = (bf16_t*)(ws + alloc((size_t)PAIRS * H_ * 2));

    hipMemsetAsync(counts, 0, E_ * 4, stream);

    router_kernel<<<TOK / 4, 256, 0, stream>>>(x, Wg, top2e, top2w, counts, xb);
    scanfill_kernel<<<1, 256, 0, stream>>>(counts, offsets, blk_e, blk_m0, nblk,
                                           top2e, pair_tok, inv);
    wtrans_kernel<<<dim3(256, 24), 256, 0, stream>>>(W11, W12, W2, W11t, W12t, W2t);

    gemm1_kernel<<<dim3(I_ / 128, MAXBLK), 256, 0, stream>>>(
        xb, W11t, W12t, counts, offsets, blk_e, blk_m0, nblk, pair_tok, fusedbuf);
    gemm2_kernel<<<dim3(H_ / 128, MAXBLK), 256, 0, stream>>>(
        fusedbuf, W2t, counts, offsets, blk_e, blk_m0, nblk, ybuf);
    combine_kernel<<<TOK, 256, 0, stream>>>(ybuf, inv, top2w, out);
}